// Round 1
// baseline (1615.701 us; speedup 1.0000x reference)
//
#include <hip/hip_runtime.h>
#include <math.h>

#define BB 1024
#define LL 40
#define EE 1024
#define RR 1024
#define AA 512

__device__ __forceinline__ float sigmoidf_(float x) { return 1.0f / (1.0f + expf(-x)); }

// ---------------------------------------------------------------------------
// Tiled FP32 GEMM: C[M,N] (+)= A[M,K] @ W[K,N] (+ bias[N])
// Tile: BM=64, BN=64, BK=16. 256 threads, 4x4 outputs per thread.
// Requires M%64==0, N%64==0, K%16==0 (true for all calls here).
// ---------------------------------------------------------------------------
template <bool ACC, bool HAS_BIAS>
__global__ __launch_bounds__(256) void gemm_f32(
    const float* __restrict__ A, const float* __restrict__ W,
    const float* __restrict__ bias, float* __restrict__ C,
    int M, int N, int K)
{
    __shared__ float As[16][64];
    __shared__ float Ws[16][64];
    const int tid = threadIdx.x;
    const int tx = tid & 15, ty = tid >> 4;
    const int m0 = blockIdx.y * 64, n0 = blockIdx.x * 64;

    const int arow = tid >> 2, akq = tid & 3;   // A: 64 rows x 4 float4 along K
    const int wkr = tid >> 4, wcq = tid & 15;   // W: 16 k-rows x 16 float4 along N

    float acc[4][4] = {};

    for (int k0 = 0; k0 < K; k0 += 16) {
        float4 a4 = *(const float4*)&A[(size_t)(m0 + arow) * K + k0 + akq * 4];
        float4 w4 = *(const float4*)&W[(size_t)(k0 + wkr) * N + n0 + wcq * 4];
        __syncthreads();
        As[akq * 4 + 0][arow] = a4.x;
        As[akq * 4 + 1][arow] = a4.y;
        As[akq * 4 + 2][arow] = a4.z;
        As[akq * 4 + 3][arow] = a4.w;
        *(float4*)&Ws[wkr][wcq * 4] = w4;
        __syncthreads();
#pragma unroll
        for (int kk = 0; kk < 16; ++kk) {
            float4 av = *(const float4*)&As[kk][ty * 4];
            float4 wv = *(const float4*)&Ws[kk][tx * 4];
            float a[4] = {av.x, av.y, av.z, av.w};
            float w[4] = {wv.x, wv.y, wv.z, wv.w};
#pragma unroll
            for (int i = 0; i < 4; ++i)
#pragma unroll
                for (int j = 0; j < 4; ++j)
                    acc[i][j] = fmaf(a[i], w[j], acc[i][j]);
        }
    }

#pragma unroll
    for (int i = 0; i < 4; ++i) {
        const int row = m0 + ty * 4 + i;
        float* cptr = &C[(size_t)row * N + n0 + tx * 4];
        float4 prev;
        if (ACC) prev = *(const float4*)cptr;
        float4 out;
        float* po = &out.x;
        const float* pp = &prev.x;
#pragma unroll
        for (int j = 0; j < 4; ++j) {
            float v = acc[i][j];
            if (HAS_BIAS) v += bias[n0 + tx * 4 + j];
            if (ACC) v += pp[j];
            po[j] = v;
        }
        *(float4*)cptr = out;
    }
}

// ---------------------------------------------------------------------------
// Attention score partials with fused tanh + Wa2w reduction.
// epart[m*8+cb] = sum_{a in col-block} tanh((V[m,:]@Wv2a[:,a]) + hq[b,a] + bv2a[a]) * Wa2w[a]
// ---------------------------------------------------------------------------
__global__ __launch_bounds__(256) void attn_e_kernel(
    const float* __restrict__ V, const float* __restrict__ Wv2a,
    const float* __restrict__ bv2a, const float* __restrict__ hq,
    const float* __restrict__ Wa2w, float* __restrict__ epart)
{
    __shared__ float As[16][64];
    __shared__ float Ws[16][64];
    __shared__ float red[64][17];
    const int tid = threadIdx.x;
    const int tx = tid & 15, ty = tid >> 4;
    const int m0 = blockIdx.y * 64, n0 = blockIdx.x * 64;

    const int arow = tid >> 2, akq = tid & 3;
    const int wkr = tid >> 4, wcq = tid & 15;

    float acc[4][4] = {};

    for (int k0 = 0; k0 < RR; k0 += 16) {
        float4 a4 = *(const float4*)&V[(size_t)(m0 + arow) * RR + k0 + akq * 4];
        float4 w4 = *(const float4*)&Wv2a[(size_t)(k0 + wkr) * AA + n0 + wcq * 4];
        __syncthreads();
        As[akq * 4 + 0][arow] = a4.x;
        As[akq * 4 + 1][arow] = a4.y;
        As[akq * 4 + 2][arow] = a4.z;
        As[akq * 4 + 3][arow] = a4.w;
        *(float4*)&Ws[wkr][wcq * 4] = w4;
        __syncthreads();
#pragma unroll
        for (int kk = 0; kk < 16; ++kk) {
            float4 av = *(const float4*)&As[kk][ty * 4];
            float4 wv = *(const float4*)&Ws[kk][tx * 4];
            float a[4] = {av.x, av.y, av.z, av.w};
            float w[4] = {wv.x, wv.y, wv.z, wv.w};
#pragma unroll
            for (int i = 0; i < 4; ++i)
#pragma unroll
                for (int j = 0; j < 4; ++j)
                    acc[i][j] = fmaf(a[i], w[j], acc[i][j]);
        }
    }

    float wa[4], bv[4];
#pragma unroll
    for (int j = 0; j < 4; ++j) {
        const int col = n0 + tx * 4 + j;
        wa[j] = Wa2w[col];
        bv[j] = bv2a[col];
    }
#pragma unroll
    for (int i = 0; i < 4; ++i) {
        const int m = m0 + ty * 4 + i;
        const int b = m / LL;
        const float* hqr = &hq[(size_t)b * AA + n0 + tx * 4];
        float s = 0.f;
#pragma unroll
        for (int j = 0; j < 4; ++j)
            s += tanhf(acc[i][j] + hqr[j] + bv[j]) * wa[j];
        red[ty * 4 + i][tx] = s;
    }
    __syncthreads();
    if (tid < 64) {
        float s = 0.f;
#pragma unroll
        for (int t = 0; t < 16; ++t) s += red[tid][t];
        epart[(size_t)(m0 + tid) * 8 + blockIdx.x] = s;
    }
}

// ---------------------------------------------------------------------------
// Per-batch softmax over L + weighted sum over V.
// ---------------------------------------------------------------------------
__global__ __launch_bounds__(256) void softmax_af_kernel(
    const float* __restrict__ epart, const float* __restrict__ V,
    const float* __restrict__ ba2w, float* __restrict__ af)
{
    const int b = blockIdx.x;
    const int tid = threadIdx.x;
    __shared__ float e_raw[LL];
    __shared__ float e_exp[LL];

    if (tid < LL) {
        const float* ep = &epart[(size_t)(b * LL + tid) * 8];
        float e = ba2w[0];
#pragma unroll
        for (int c = 0; c < 8; ++c) e += ep[c];
        e_raw[tid] = e;
    }
    __syncthreads();
    float mx = -1e30f;
#pragma unroll
    for (int l = 0; l < LL; ++l) mx = fmaxf(mx, e_raw[l]);
    if (tid < LL) e_exp[tid] = expf(e_raw[tid] - mx);
    __syncthreads();
    float sum = 0.f;
#pragma unroll
    for (int l = 0; l < LL; ++l) sum += e_exp[l];
    const float inv = 1.f / sum;

    for (int r = tid; r < RR; r += 256) {
        const float* vp = &V[(size_t)b * LL * RR + r];
        float acc = 0.f;
#pragma unroll 8
        for (int l = 0; l < LL; ++l) acc += e_exp[l] * vp[(size_t)l * RR];
        af[(size_t)b * RR + r] = acc * inv;
    }
}

__global__ __launch_bounds__(256) void gate_elem_kernel(
    const float* __restrict__ g, const float* __restrict__ pos,
    float* __restrict__ gp, int n)
{
    const int i = blockIdx.x * 256 + threadIdx.x;
    if (i < n) {
        const float gv = fmaxf(g[i], 0.f);
        gp[i] = gv * pos[i] + pos[i];
    }
}

__global__ __launch_bounds__(256) void lstm_finish_kernel(
    const float* __restrict__ s, const float* __restrict__ c_in,
    const float* __restrict__ h_in, const float* __restrict__ mask,
    float* __restrict__ h_out, float* __restrict__ h_out2,
    float* __restrict__ c_out)
{
    const int i = blockIdx.x * 256 + threadIdx.x;  // [0, B*R)
    const int b = i >> 10;                          // R = 1024
    const int r = i & 1023;
    const float* sb = &s[(size_t)b * 4 * RR];
    const float ig = sigmoidf_(sb[r]);
    const float fg = sigmoidf_(sb[RR + r]);
    const float og = sigmoidf_(sb[2 * RR + r]);
    const float g  = tanhf(sb[3 * RR + r]);
    const float m = mask[b];
    const float c = c_in[i];
    float cn = fg * c + ig * g;
    cn = cn * m + c * (1.f - m);
    const float h = h_in[i];
    float hn = og * tanhf(cn);
    hn = hn * m + h * (1.f - m);
    h_out[i] = hn;
    if (h_out2) h_out2[i] = hn;
    c_out[i] = cn;
}

extern "C" void kernel_launch(void* const* d_in, const int* in_sizes, int n_in,
                              void* d_out, int out_size, void* d_ws, size_t ws_size,
                              hipStream_t stream) {
    const float* xt   = (const float*)d_in[0];
    const float* mask = (const float*)d_in[1];
    const float* V    = (const float*)d_in[2];
    const float* pos  = (const float*)d_in[3];
    const float* h1   = (const float*)d_in[4];
    const float* c1   = (const float*)d_in[5];
    const float* h2   = (const float*)d_in[6];
    const float* c2   = (const float*)d_in[7];
    const float* Wg   = (const float*)d_in[8];
    const float* bg   = (const float*)d_in[9];
    const float* Wi1  = (const float*)d_in[10];
    const float* bi1  = (const float*)d_in[11];
    const float* Wa1  = (const float*)d_in[12];
    const float* ba1  = (const float*)d_in[13];
    const float* Wh1  = (const float*)d_in[14];
    const float* bh1  = (const float*)d_in[15];
    const float* Wi2  = (const float*)d_in[16];
    const float* bi2  = (const float*)d_in[17];
    const float* Wa2  = (const float*)d_in[18];
    const float* ba2  = (const float*)d_in[19];
    const float* Wh2  = (const float*)d_in[20];
    const float* bh2  = (const float*)d_in[21];
    const float* Wv2a = (const float*)d_in[22];
    const float* bv2a = (const float*)d_in[23];
    const float* Wh2a = (const float*)d_in[24];
    const float* bh2a = (const float*)d_in[25];
    const float* Wa2w = (const float*)d_in[26];
    const float* ba2w = (const float*)d_in[27];

    float* out = (float*)d_out;
    float* out2  = out;                            // [B,R]
    float* out1  = out + (size_t)BB * RR;
    float* c1n   = out + 2 * (size_t)BB * RR;
    float* out2b = out + 3 * (size_t)BB * RR;
    float* c2n   = out + 4 * (size_t)BB * RR;

    float* ws    = (float*)d_ws;
    float* hq    = ws;                             // B*A
    float* epart = hq + (size_t)BB * AA;           // B*L*8
    float* af    = epart + (size_t)BB * LL * 8;    // B*R
    float* gbuf  = af + (size_t)BB * RR;           // B*R
    float* gp    = gbuf + (size_t)BB * RR;         // B*R
    float* sbuf  = gp + (size_t)BB * RR;           // B*4R (reused for both layers)

    const dim3 blk(256);

    // ---- attention path ----
    gemm_f32<false, true><<<dim3(AA / 64, BB / 64), blk, 0, stream>>>(h1, Wh2a, bh2a, hq, BB, AA, RR);
    gemm_f32<true, false><<<dim3(AA / 64, BB / 64), blk, 0, stream>>>(h2, Wh2a + (size_t)RR * AA, nullptr, hq, BB, AA, RR);
    attn_e_kernel<<<dim3(AA / 64, BB * LL / 64), blk, 0, stream>>>(V, Wv2a, bv2a, hq, Wa2w, epart);
    softmax_af_kernel<<<dim3(BB), blk, 0, stream>>>(epart, V, ba2w, af);

    // ---- gate ----
    gemm_f32<false, true><<<dim3(RR / 64, BB / 64), blk, 0, stream>>>(xt, Wg, bg, gbuf, BB, RR, EE);
    gate_elem_kernel<<<dim3(BB * RR / 256), blk, 0, stream>>>(gbuf, pos, gp, BB * RR);

    // ---- LSTM layer 1 ----
    gemm_f32<false, true><<<dim3(4 * RR / 64, BB / 64), blk, 0, stream>>>(xt, Wi1, bi1, sbuf, BB, 4 * RR, EE);
    gemm_f32<true, true><<<dim3(4 * RR / 64, BB / 64), blk, 0, stream>>>(gp, Wa1, ba1, sbuf, BB, 4 * RR, RR);
    gemm_f32<true, true><<<dim3(4 * RR / 64, BB / 64), blk, 0, stream>>>(h1, Wh1, bh1, sbuf, BB, 4 * RR, RR);
    lstm_finish_kernel<<<dim3(BB * RR / 256), blk, 0, stream>>>(sbuf, c1, h1, mask, out1, nullptr, c1n);

    // ---- LSTM layer 2 ----
    gemm_f32<false, true><<<dim3(4 * RR / 64, BB / 64), blk, 0, stream>>>(out1, Wi2, bi2, sbuf, BB, 4 * RR, RR);
    gemm_f32<true, true><<<dim3(4 * RR / 64, BB / 64), blk, 0, stream>>>(af, Wa2, ba2, sbuf, BB, 4 * RR, RR);
    gemm_f32<true, true><<<dim3(4 * RR / 64, BB / 64), blk, 0, stream>>>(h2, Wh2, bh2, sbuf, BB, 4 * RR, RR);
    lstm_finish_kernel<<<dim3(BB * RR / 256), blk, 0, stream>>>(sbuf, c2, h2, mask, out2, out2b, c2n);
}

// Round 2
// 503.302 us; speedup vs baseline: 3.2102x; 3.2102x over previous
//
#include <hip/hip_runtime.h>
#include <math.h>

#define BB 1024
#define LL 40
#define RR 1024

using short8 = __attribute__((ext_vector_type(8))) short;
using f32x4  = __attribute__((ext_vector_type(4))) float;

__device__ __forceinline__ ushort f2bf(float f) {
    union { float f; unsigned u; } a; a.f = f;
    unsigned r = a.u + 0x7fffu + ((a.u >> 16) & 1u);  // RNE
    return (ushort)(r >> 16);
}
__device__ __forceinline__ float ftanh(float x) {
    float cx = fminf(fmaxf(x, -15.f), 15.f);
    float e = __expf(2.f * cx);
    return (e - 1.f) / (e + 1.f);
}
__device__ __forceinline__ float fsigmoid(float x) {
    float cx = fminf(fmaxf(x, -30.f), 30.f);
    return 1.f / (1.f + __expf(-cx));
}

// ---------------------------------------------------------------------------
// BF16 MFMA GEMM, 128x128 tile, BK=32, 256 threads (4 waves, 2x2 of 64x64).
// C[M,N] = sum_p A_p[M,1024] @ W_p[1024,N]  (fp32 in, bf16 MFMA, fp32 acc)
// All part-K are 1024. EPI: 0 = bias+store, 2 = attn tanh-reduce, 3 = split-K
// partial store (no bias). SK = split-K factor (grid.z).
// ---------------------------------------------------------------------------
template <int NP, int EPI, int SK>
__global__ __launch_bounds__(256) void gemm_bf16(
    const float* __restrict__ A0, const float* __restrict__ A1, const float* __restrict__ A2,
    const float* __restrict__ W0, const float* __restrict__ W1, const float* __restrict__ W2,
    const float* __restrict__ b0, const float* __restrict__ b1, const float* __restrict__ b2,
    float* __restrict__ C, int M, int N,
    const float* __restrict__ hq, const float* __restrict__ bv2a,
    const float* __restrict__ Wa2w, float* __restrict__ epart)
{
    __shared__ ushort Alds[128 * 40];   // [row][k] padded to 40 (80B rows, 16B-aligned)
    __shared__ ushort Blds[128 * 40];   // [col][k] padded to 40
    __shared__ float  red2[128][2];

    const int t    = threadIdx.x;
    const int lane = t & 63;
    const int wave = t >> 6;
    const int wm = wave >> 1, wn = wave & 1;
    const int m0 = blockIdx.y * 128, n0 = blockIdx.x * 128;
    const int srow = t & 127, sh = t >> 7;   // staging: row/col, k-half

    f32x4 acc[4][4];
#pragma unroll
    for (int i = 0; i < 4; ++i)
#pragma unroll
        for (int j = 0; j < 4; ++j) acc[i][j] = (f32x4){0.f, 0.f, 0.f, 0.f};

    const int total = NP * 32;           // K-steps of 32 over all parts
    const int per   = total / SK;
    const int s0    = blockIdx.z * per;

    for (int s = s0; s < s0 + per; ++s) {
        const int p  = (NP == 1) ? 0 : (s >> 5);
        const int k0 = (s & 31) << 5;
        const float* Ap = (p == 0) ? A0 : ((p == 1) ? A1 : A2);
        const float* Wp = (p == 0) ? W0 : ((p == 1) ? W1 : W2);

        // A: thread loads 16 contiguous k (64B) of one row
        const float* ag = Ap + (size_t)(m0 + srow) * 1024 + k0 + sh * 16;
        float4 a0 = ((const float4*)ag)[0];
        float4 a1 = ((const float4*)ag)[1];
        float4 a2 = ((const float4*)ag)[2];
        float4 a3 = ((const float4*)ag)[3];
        // B: thread loads 16 k's of one column (each load coalesced across lanes)
        const float* wg = Wp + (size_t)(k0 + sh * 16) * N + n0 + srow;
        float w[16];
#pragma unroll
        for (int j = 0; j < 16; ++j) w[j] = wg[(size_t)j * N];

        __syncthreads();   // previous iteration's reads done
        {
            ushort* adst = &Alds[srow * 40 + sh * 16];
            short8 v0, v1;
            v0[0] = f2bf(a0.x); v0[1] = f2bf(a0.y); v0[2] = f2bf(a0.z); v0[3] = f2bf(a0.w);
            v0[4] = f2bf(a1.x); v0[5] = f2bf(a1.y); v0[6] = f2bf(a1.z); v0[7] = f2bf(a1.w);
            v1[0] = f2bf(a2.x); v1[1] = f2bf(a2.y); v1[2] = f2bf(a2.z); v1[3] = f2bf(a2.w);
            v1[4] = f2bf(a3.x); v1[5] = f2bf(a3.y); v1[6] = f2bf(a3.z); v1[7] = f2bf(a3.w);
            *(short8*)adst = v0;
            *(short8*)(adst + 8) = v1;
            ushort* bdst = &Blds[srow * 40 + sh * 16];
            short8 u0, u1;
#pragma unroll
            for (int j = 0; j < 8; ++j) { u0[j] = f2bf(w[j]); u1[j] = f2bf(w[8 + j]); }
            *(short8*)bdst = u0;
            *(short8*)(bdst + 8) = u1;
        }
        __syncthreads();

        short8 aF[4], bF[4];
#pragma unroll
        for (int mi = 0; mi < 4; ++mi)
            aF[mi] = *(const short8*)&Alds[(wm * 64 + mi * 16 + (lane & 15)) * 40 + (lane >> 4) * 8];
#pragma unroll
        for (int ni = 0; ni < 4; ++ni)
            bF[ni] = *(const short8*)&Blds[(wn * 64 + ni * 16 + (lane & 15)) * 40 + (lane >> 4) * 8];
#pragma unroll
        for (int mi = 0; mi < 4; ++mi)
#pragma unroll
            for (int ni = 0; ni < 4; ++ni)
                acc[mi][ni] = __builtin_amdgcn_mfma_f32_16x16x32_bf16(aF[mi], bF[ni], acc[mi][ni], 0, 0, 0);
    }

    if constexpr (EPI == 0) {
#pragma unroll
        for (int ni = 0; ni < 4; ++ni) {
            const int col = n0 + wn * 64 + ni * 16 + (lane & 15);
            float bs = b0[col];
            if (NP > 1) bs += b1[col];
            if (NP > 2) bs += b2[col];
#pragma unroll
            for (int mi = 0; mi < 4; ++mi) {
                const int row = m0 + wm * 64 + mi * 16 + ((lane >> 4) << 2);
#pragma unroll
                for (int r = 0; r < 4; ++r)
                    C[(size_t)(row + r) * N + col] = acc[mi][ni][r] + bs;
            }
        }
    } else if constexpr (EPI == 3) {
        float* Cz = C + (size_t)blockIdx.z * M * N;
#pragma unroll
        for (int ni = 0; ni < 4; ++ni) {
            const int col = n0 + wn * 64 + ni * 16 + (lane & 15);
#pragma unroll
            for (int mi = 0; mi < 4; ++mi) {
                const int row = m0 + wm * 64 + mi * 16 + ((lane >> 4) << 2);
#pragma unroll
                for (int r = 0; r < 4; ++r)
                    Cz[(size_t)(row + r) * N + col] = acc[mi][ni][r];
            }
        }
    } else if constexpr (EPI == 2) {
        // e-partial: sum over this block's 128 cols of tanh(acc+hq+bv)*wa
        float wa[4], bv[4];
        int coln[4];
#pragma unroll
        for (int ni = 0; ni < 4; ++ni) {
            coln[ni] = n0 + wn * 64 + ni * 16 + (lane & 15);
            wa[ni] = Wa2w[coln[ni]];
            bv[ni] = bv2a[coln[ni]];
        }
#pragma unroll
        for (int mi = 0; mi < 4; ++mi) {
            const int rowb = m0 + wm * 64 + mi * 16 + ((lane >> 4) << 2);
#pragma unroll
            for (int r = 0; r < 4; ++r) {
                const int row = rowb + r;
                const int b = row / LL;
                float v = 0.f;
#pragma unroll
                for (int ni = 0; ni < 4; ++ni) {
                    float x = acc[mi][ni][r] + hq[(size_t)b * 512 + coln[ni]] + bv[ni];
                    v += ftanh(x) * wa[ni];
                }
                v += __shfl_xor(v, 1);
                v += __shfl_xor(v, 2);
                v += __shfl_xor(v, 4);
                v += __shfl_xor(v, 8);
                if ((lane & 15) == 0) red2[rowb - m0 + r][wn] = v;
            }
        }
        __syncthreads();
        if (t < 128)
            epart[(size_t)(m0 + t) * 4 + blockIdx.x] = red2[t][0] + red2[t][1];
    }
}

// ---------------------------------------------------------------------------
__global__ __launch_bounds__(256) void reduce_hq_kernel(
    const float* __restrict__ part, const float* __restrict__ bias, float* __restrict__ hq)
{
    const int i = blockIdx.x * 256 + threadIdx.x;   // < 1024*512
    float s = bias[i & 511];
#pragma unroll
    for (int z = 0; z < 8; ++z) s += part[(size_t)z * 524288 + i];
    hq[i] = s;
}

__global__ __launch_bounds__(256) void reduce_gate_kernel(
    const float* __restrict__ part, const float* __restrict__ bias,
    const float* __restrict__ pos, float* __restrict__ gp)
{
    const int i = blockIdx.x * 256 + threadIdx.x;   // < 1024*1024
    float s = bias[i & 1023];
#pragma unroll
    for (int z = 0; z < 4; ++z) s += part[(size_t)z * 1048576 + i];
    const float g = fmaxf(s, 0.f);
    gp[i] = g * pos[i] + pos[i];
}

// ---------------------------------------------------------------------------
__global__ __launch_bounds__(256) void softmax_af_kernel(
    const float* __restrict__ epart, const float* __restrict__ V,
    const float* __restrict__ ba2w, float* __restrict__ af)
{
    const int b = blockIdx.x;
    const int tid = threadIdx.x;
    __shared__ float e_raw[LL];
    __shared__ float e_exp[LL];

    if (tid < LL) {
        const float* ep = &epart[(size_t)(b * LL + tid) * 4];
        float e = ba2w[0];
#pragma unroll
        for (int c = 0; c < 4; ++c) e += ep[c];
        e_raw[tid] = e;
    }
    __syncthreads();
    float mx = -1e30f;
#pragma unroll
    for (int l = 0; l < LL; ++l) mx = fmaxf(mx, e_raw[l]);
    if (tid < LL) e_exp[tid] = __expf(e_raw[tid] - mx);
    __syncthreads();
    float sum = 0.f;
#pragma unroll
    for (int l = 0; l < LL; ++l) sum += e_exp[l];
    const float inv = 1.f / sum;

    for (int r = tid; r < RR; r += 256) {
        const float* vp = &V[(size_t)b * LL * RR + r];
        float a = 0.f;
#pragma unroll 8
        for (int l = 0; l < LL; ++l) a += e_exp[l] * vp[(size_t)l * RR];
        af[(size_t)b * RR + r] = a * inv;
    }
}

__global__ __launch_bounds__(256) void lstm_finish_kernel(
    const float* __restrict__ s, const float* __restrict__ c_in,
    const float* __restrict__ h_in, const float* __restrict__ mask,
    float* __restrict__ h_out, float* __restrict__ h_out2,
    float* __restrict__ c_out)
{
    const int i = blockIdx.x * 256 + threadIdx.x;  // [0, B*R)
    const int b = i >> 10;
    const int r = i & 1023;
    const float* sb = &s[(size_t)b * 4 * RR];
    const float ig = fsigmoid(sb[r]);
    const float fg = fsigmoid(sb[RR + r]);
    const float og = fsigmoid(sb[2 * RR + r]);
    const float g  = ftanh(sb[3 * RR + r]);
    const float m = mask[b];
    const float c = c_in[i];
    float cn = fg * c + ig * g;
    cn = cn * m + c * (1.f - m);
    const float h = h_in[i];
    float hn = og * ftanh(cn);
    hn = hn * m + h * (1.f - m);
    h_out[i] = hn;
    if (h_out2) h_out2[i] = hn;
    c_out[i] = cn;
}

extern "C" void kernel_launch(void* const* d_in, const int* in_sizes, int n_in,
                              void* d_out, int out_size, void* d_ws, size_t ws_size,
                              hipStream_t stream) {
    const float* xt   = (const float*)d_in[0];
    const float* mask = (const float*)d_in[1];
    const float* V    = (const float*)d_in[2];
    const float* pos  = (const float*)d_in[3];
    const float* h1   = (const float*)d_in[4];
    const float* c1   = (const float*)d_in[5];
    const float* h2   = (const float*)d_in[6];
    const float* c2   = (const float*)d_in[7];
    const float* Wg   = (const float*)d_in[8];
    const float* bg   = (const float*)d_in[9];
    const float* Wi1  = (const float*)d_in[10];
    const float* bi1  = (const float*)d_in[11];
    const float* Wa1  = (const float*)d_in[12];
    const float* ba1  = (const float*)d_in[13];
    const float* Wh1  = (const float*)d_in[14];
    const float* bh1  = (const float*)d_in[15];
    const float* Wi2  = (const float*)d_in[16];
    const float* bi2  = (const float*)d_in[17];
    const float* Wa2  = (const float*)d_in[18];
    const float* ba2  = (const float*)d_in[19];
    const float* Wh2  = (const float*)d_in[20];
    const float* bh2  = (const float*)d_in[21];
    const float* Wv2a = (const float*)d_in[22];
    const float* bv2a = (const float*)d_in[23];
    const float* Wh2a = (const float*)d_in[24];
    const float* bh2a = (const float*)d_in[25];
    const float* Wa2w = (const float*)d_in[26];
    const float* ba2w = (const float*)d_in[27];

    float* out = (float*)d_out;
    float* out2  = out;
    float* out1  = out + (size_t)BB * RR;
    float* c1n   = out + 2 * (size_t)BB * RR;
    float* out2b = out + 3 * (size_t)BB * RR;
    float* c2n   = out + 4 * (size_t)BB * RR;

    float* ws    = (float*)d_ws;
    float* hqb   = ws;                           // 524288
    float* epart = hqb + 524288;                 // 40960*4
    float* af    = epart + 163840;               // 1M
    float* gp    = af + 1048576;                 // 1M
    float* sbuf  = gp + 1048576;                 // 4M, aliased as split-K partials
    float* partK = sbuf;

    const dim3 blk(256);

    // hq = [h1,h2] @ Wh2a + bh2a   (split-K x8 into partials, then reduce)
    gemm_bf16<2, 3, 8><<<dim3(4, 8, 8), blk, 0, stream>>>(
        h1, h2, nullptr, Wh2a, Wh2a + (size_t)1024 * 512, nullptr,
        nullptr, nullptr, nullptr, partK, 1024, 512, nullptr, nullptr, nullptr, nullptr);
    reduce_hq_kernel<<<dim3(2048), blk, 0, stream>>>(partK, bh2a, hqb);

    // gate partials: xt @ Wg (split-K x4), then fused relu*pos+pos
    gemm_bf16<1, 3, 4><<<dim3(8, 8, 4), blk, 0, stream>>>(
        xt, nullptr, nullptr, Wg, nullptr, nullptr,
        nullptr, nullptr, nullptr, partK, 1024, 1024, nullptr, nullptr, nullptr, nullptr);
    reduce_gate_kernel<<<dim3(4096), blk, 0, stream>>>(partK, bg, pos, gp);

    // attention scores: V @ Wv2a with fused tanh-reduce epilogue -> epart
    gemm_bf16<1, 2, 1><<<dim3(4, 320, 1), blk, 0, stream>>>(
        V, nullptr, nullptr, Wv2a, nullptr, nullptr,
        nullptr, nullptr, nullptr, nullptr, 40960, 512, hqb, bv2a, Wa2w, epart);
    softmax_af_kernel<<<dim3(BB), blk, 0, stream>>>(epart, V, ba2w, af);

    // LSTM layer 1: fused K (xt|gp|h1) @ (Wi1|Wa1|Wh1)
    gemm_bf16<3, 0, 1><<<dim3(32, 8, 1), blk, 0, stream>>>(
        xt, gp, h1, Wi1, Wa1, Wh1, bi1, ba1, bh1,
        sbuf, 1024, 4096, nullptr, nullptr, nullptr, nullptr);
    lstm_finish_kernel<<<dim3(4096), blk, 0, stream>>>(sbuf, c1, h1, mask, out1, nullptr, c1n);

    // LSTM layer 2: fused K (out1|af|h2) @ (Wi2|Wa2|Wh2)
    gemm_bf16<3, 0, 1><<<dim3(32, 8, 1), blk, 0, stream>>>(
        out1, af, h2, Wi2, Wa2, Wh2, bi2, ba2, bh2,
        sbuf, 1024, 4096, nullptr, nullptr, nullptr, nullptr);
    lstm_finish_kernel<<<dim3(4096), blk, 0, stream>>>(sbuf, c2, h2, mask, out2, out2b, c2n);
}

// Round 3
// 323.230 us; speedup vs baseline: 4.9986x; 1.5571x over previous
//
#include <hip/hip_runtime.h>
#include <math.h>

#define BB 1024
#define LL 40
#define RR 1024

using short8 = __attribute__((ext_vector_type(8))) short;
using us8    = __attribute__((ext_vector_type(8))) unsigned short;
using f32x4  = __attribute__((ext_vector_type(4))) float;

__device__ __forceinline__ ushort f2bf(float f) {
    union { float f; unsigned u; } a; a.f = f;
    unsigned r = a.u + 0x7fffu + ((a.u >> 16) & 1u);  // RNE
    return (ushort)(r >> 16);
}
__device__ __forceinline__ float bf2f(ushort u) {
    union { unsigned u; float f; } a; a.u = ((unsigned)u) << 16;
    return a.f;
}
__device__ __forceinline__ float ftanh(float x) {
    float cx = fminf(fmaxf(x, -15.f), 15.f);
    float e = __expf(2.f * cx);
    return (e - 1.f) / (e + 1.f);
}
__device__ __forceinline__ float fsigmoid(float x) {
    float cx = fminf(fmaxf(x, -30.f), 30.f);
    return 1.f / (1.f + __expf(-cx));
}

// ---------------------------------------------------------------------------
// Flat fp32 -> bf16 convert (8 elems/thread, exact grids only)
// ---------------------------------------------------------------------------
__global__ __launch_bounds__(256) void conv_bf16_kernel(
    const float* __restrict__ src, ushort* __restrict__ dst, int n8)
{
    const int i = blockIdx.x * 256 + threadIdx.x;
    if (i >= n8) return;
    const float4* s4 = (const float4*)(src + (size_t)i * 8);
    float4 x = s4[0], y = s4[1];
    us8 v;
    v[0] = f2bf(x.x); v[1] = f2bf(x.y); v[2] = f2bf(x.z); v[3] = f2bf(x.w);
    v[4] = f2bf(y.x); v[5] = f2bf(y.y); v[6] = f2bf(y.z); v[7] = f2bf(y.w);
    ((us8*)dst)[i] = v;
}

struct CP3 { const float* in[3]; ushort* out[3]; };
__global__ __launch_bounds__(256) void conv_bf16_batch3_kernel(CP3 p, int n8)
{
    const int z = blockIdx.y;
    const int i = blockIdx.x * 256 + threadIdx.x;
    if (i >= n8) return;
    const float4* s4 = (const float4*)(p.in[z] + (size_t)i * 8);
    float4 x = s4[0], y = s4[1];
    us8 v;
    v[0] = f2bf(x.x); v[1] = f2bf(x.y); v[2] = f2bf(x.z); v[3] = f2bf(x.w);
    v[4] = f2bf(y.x); v[5] = f2bf(y.y); v[6] = f2bf(y.z); v[7] = f2bf(y.w);
    ((us8*)p.out[z])[i] = v;
}

// ---------------------------------------------------------------------------
// Transpose + convert: in fp32 [K=1024][N] -> out bf16 [N][1024].
// 64x64 tiles via LDS. grid = (maxN/64, 16, ntensors), skip if beyond N[z].
// ---------------------------------------------------------------------------
struct TP6 { const float* in[6]; ushort* out[6]; int N[6]; };
__global__ __launch_bounds__(256) void transpose_conv_kernel(TP6 p)
{
    const int z = blockIdx.z;
    const int Nn = p.N[z];
    const int n0 = blockIdx.x * 64;
    if (n0 >= Nn) return;
    const int k0 = blockIdx.y * 64;
    const float* in = p.in[z];
    ushort* out = p.out[z];

    __shared__ float tile[64][65];
    const int t = threadIdx.x;
    const int tx = t & 63, ty = t >> 6;   // ty in 0..3
#pragma unroll
    for (int r = 0; r < 16; ++r) {
        const int row = ty * 16 + r;
        tile[row][tx] = in[(size_t)(k0 + row) * Nn + n0 + tx];
    }
    __syncthreads();
    const int n = t >> 2, kq = t & 3;
    us8 v0, v1;
#pragma unroll
    for (int j = 0; j < 8; ++j) v0[j] = f2bf(tile[kq * 16 + j][n]);
#pragma unroll
    for (int j = 0; j < 8; ++j) v1[j] = f2bf(tile[kq * 16 + 8 + j][n]);
    ushort* op = out + (size_t)(n0 + n) * 1024 + k0 + kq * 16;
    *(us8*)op = v0;
    *((us8*)op + 1) = v1;
}

// ---------------------------------------------------------------------------
// BF16 MFMA GEMM, 128x128 tile, BK=64, 256 threads (4 waves, 2x2 of 64x64).
// A_p: bf16 [M][1024] row-major. W_p: bf16 [N][1024] (pre-transposed).
// C = sum_p A_p @ W_p^T. EPI: 0 = bias+store, 2 = attn tanh-reduce,
// 3 = split-K partial store. Register-prefetch staging.
// ---------------------------------------------------------------------------
template <int NP, int EPI, int SK>
__global__ __launch_bounds__(256) void gemm_bf16(
    const ushort* __restrict__ A0, const ushort* __restrict__ A1, const ushort* __restrict__ A2,
    const ushort* __restrict__ W0, const ushort* __restrict__ W1, const ushort* __restrict__ W2,
    const float* __restrict__ b0, const float* __restrict__ b1, const float* __restrict__ b2,
    float* __restrict__ C, int M, int N,
    const float* __restrict__ hq, const float* __restrict__ bv2a,
    const float* __restrict__ Wa2w, float* __restrict__ epart)
{
    __shared__ ushort Alds[128 * 72];
    __shared__ ushort Blds[128 * 72];
    __shared__ float  red2[128][2];

    const int t = threadIdx.x;
    const int lane = t & 63;
    const int wave = t >> 6;
    const int wm = wave >> 1, wn = wave & 1;

    int bx, by;
    if constexpr (EPI == 2) {
        // XCD-chunked bijective swizzle: nwg = 4*320 = 1280 = 8*160
        const int lin = blockIdx.y * 4 + blockIdx.x;
        const int nl = (lin & 7) * 160 + (lin >> 3);
        bx = nl & 3; by = nl >> 2;
    } else {
        bx = blockIdx.x; by = blockIdx.y;
    }
    const int m0 = by * 128, n0 = bx * 128;

    const int srow = t >> 1, skh = t & 1;      // staging: row 0..127, k-half
    const int soff = srow * 72 + skh * 32;

    f32x4 acc[4][4];
#pragma unroll
    for (int i = 0; i < 4; ++i)
#pragma unroll
        for (int j = 0; j < 4; ++j) acc[i][j] = (f32x4){0.f, 0.f, 0.f, 0.f};

    const int total = NP * 16;            // K-steps of 64
    const int per   = total / SK;
    const int s0    = blockIdx.z * per;
    const int sEnd  = s0 + per;

    short8 ra[4], rw[4];
    {
        const int p  = (NP == 1) ? 0 : (s0 >> 4);
        const int k0 = (s0 & 15) << 6;
        const ushort* Ap = (p == 0) ? A0 : ((p == 1) ? A1 : A2);
        const ushort* Wp = (p == 0) ? W0 : ((p == 1) ? W1 : W2);
        const short8* ag = (const short8*)(Ap + (size_t)(m0 + srow) * 1024 + k0 + skh * 32);
        const short8* wg = (const short8*)(Wp + (size_t)(n0 + srow) * 1024 + k0 + skh * 32);
#pragma unroll
        for (int j = 0; j < 4; ++j) { ra[j] = ag[j]; rw[j] = wg[j]; }
    }

    for (int s = s0; s < sEnd; ++s) {
        __syncthreads();   // previous iteration's fragment reads done
#pragma unroll
        for (int j = 0; j < 4; ++j) {
            *(short8*)&Alds[soff + j * 8] = ra[j];
            *(short8*)&Blds[soff + j * 8] = rw[j];
        }
        __syncthreads();

        if (s + 1 < sEnd) {   // prefetch next tile into regs (overlaps MFMA)
            const int sn = s + 1;
            const int p  = (NP == 1) ? 0 : (sn >> 4);
            const int k0 = (sn & 15) << 6;
            const ushort* Ap = (p == 0) ? A0 : ((p == 1) ? A1 : A2);
            const ushort* Wp = (p == 0) ? W0 : ((p == 1) ? W1 : W2);
            const short8* ag = (const short8*)(Ap + (size_t)(m0 + srow) * 1024 + k0 + skh * 32);
            const short8* wg = (const short8*)(Wp + (size_t)(n0 + srow) * 1024 + k0 + skh * 32);
#pragma unroll
            for (int j = 0; j < 4; ++j) { ra[j] = ag[j]; rw[j] = wg[j]; }
        }

#pragma unroll
        for (int ks = 0; ks < 2; ++ks) {
            short8 aF[4], bF[4];
#pragma unroll
            for (int mi = 0; mi < 4; ++mi)
                aF[mi] = *(const short8*)&Alds[(wm * 64 + mi * 16 + (lane & 15)) * 72 + ks * 32 + (lane >> 4) * 8];
#pragma unroll
            for (int ni = 0; ni < 4; ++ni)
                bF[ni] = *(const short8*)&Blds[(wn * 64 + ni * 16 + (lane & 15)) * 72 + ks * 32 + (lane >> 4) * 8];
#pragma unroll
            for (int mi = 0; mi < 4; ++mi)
#pragma unroll
                for (int ni = 0; ni < 4; ++ni)
                    acc[mi][ni] = __builtin_amdgcn_mfma_f32_16x16x32_bf16(aF[mi], bF[ni], acc[mi][ni], 0, 0, 0);
        }
    }

    if constexpr (EPI == 0) {
#pragma unroll
        for (int ni = 0; ni < 4; ++ni) {
            const int col = n0 + wn * 64 + ni * 16 + (lane & 15);
            float bs = b0[col];
            if (NP > 1) bs += b1[col];
            if (NP > 2) bs += b2[col];
#pragma unroll
            for (int mi = 0; mi < 4; ++mi) {
                const int row = m0 + wm * 64 + mi * 16 + ((lane >> 4) << 2);
#pragma unroll
                for (int r = 0; r < 4; ++r)
                    C[(size_t)(row + r) * N + col] = acc[mi][ni][r] + bs;
            }
        }
    } else if constexpr (EPI == 3) {
        float* Cz = C + (size_t)blockIdx.z * M * N;
#pragma unroll
        for (int ni = 0; ni < 4; ++ni) {
            const int col = n0 + wn * 64 + ni * 16 + (lane & 15);
#pragma unroll
            for (int mi = 0; mi < 4; ++mi) {
                const int row = m0 + wm * 64 + mi * 16 + ((lane >> 4) << 2);
#pragma unroll
                for (int r = 0; r < 4; ++r)
                    Cz[(size_t)(row + r) * N + col] = acc[mi][ni][r];
            }
        }
    } else if constexpr (EPI == 2) {
        float wa[4], bv[4];
        int coln[4];
#pragma unroll
        for (int ni = 0; ni < 4; ++ni) {
            coln[ni] = n0 + wn * 64 + ni * 16 + (lane & 15);
            wa[ni] = Wa2w[coln[ni]];
            bv[ni] = bv2a[coln[ni]];
        }
#pragma unroll
        for (int mi = 0; mi < 4; ++mi) {
            const int rowb = m0 + wm * 64 + mi * 16 + ((lane >> 4) << 2);
#pragma unroll
            for (int r = 0; r < 4; ++r) {
                const int row = rowb + r;
                const int b = row / LL;
                float v = 0.f;
#pragma unroll
                for (int ni = 0; ni < 4; ++ni) {
                    float x = acc[mi][ni][r] + hq[(size_t)b * 512 + coln[ni]] + bv[ni];
                    v += ftanh(x) * wa[ni];
                }
                v += __shfl_xor(v, 1);
                v += __shfl_xor(v, 2);
                v += __shfl_xor(v, 4);
                v += __shfl_xor(v, 8);
                if ((lane & 15) == 0) red2[rowb - m0 + r][wn] = v;
            }
        }
        __syncthreads();
        if (t < 128)
            epart[(size_t)(m0 + t) * 4 + bx] = red2[t][0] + red2[t][1];
    }
}

// ---------------------------------------------------------------------------
__global__ __launch_bounds__(256) void reduce_hq_kernel(
    const float* __restrict__ part, const float* __restrict__ bias, float* __restrict__ hq)
{
    const int i = blockIdx.x * 256 + threadIdx.x;   // < 1024*512
    float s = bias[i & 511];
#pragma unroll
    for (int z = 0; z < 8; ++z) s += part[(size_t)z * 524288 + i];
    hq[i] = s;
}

__global__ __launch_bounds__(256) void reduce_gate_kernel(
    const float* __restrict__ part, const float* __restrict__ bias,
    const float* __restrict__ pos, ushort* __restrict__ gpb)
{
    const int i = blockIdx.x * 256 + threadIdx.x;   // < 1024*1024
    float s = bias[i & 1023];
#pragma unroll
    for (int z = 0; z < 4; ++z) s += part[(size_t)z * 1048576 + i];
    const float g = fmaxf(s, 0.f);
    gpb[i] = f2bf(g * pos[i] + pos[i]);
}

// ---------------------------------------------------------------------------
// Per-batch softmax over L + weighted sum over bf16 V. Writes bf16 af.
// ---------------------------------------------------------------------------
__global__ __launch_bounds__(256) void softmax_af_kernel(
    const float* __restrict__ epart, const ushort* __restrict__ Vb,
    const float* __restrict__ ba2w, ushort* __restrict__ afb)
{
    const int b = blockIdx.x;
    const int tid = threadIdx.x;
    __shared__ float e_raw[LL];
    __shared__ float e_exp[LL];

    if (tid < LL) {
        const float* ep = &epart[(size_t)(b * LL + tid) * 4];
        float e = ba2w[0];
#pragma unroll
        for (int c = 0; c < 4; ++c) e += ep[c];
        e_raw[tid] = e;
    }
    __syncthreads();
    float mx = -1e30f;
#pragma unroll
    for (int l = 0; l < LL; ++l) mx = fmaxf(mx, e_raw[l]);
    if (tid < LL) e_exp[tid] = __expf(e_raw[tid] - mx);
    __syncthreads();
    float sum = 0.f;
#pragma unroll
    for (int l = 0; l < LL; ++l) sum += e_exp[l];
    const float inv = 1.f / sum;

    const int r4 = tid * 4;                         // 256 threads * 4 = 1024 cols
    const ushort* vp = &Vb[(size_t)b * LL * RR + r4];
    float a0 = 0.f, a1 = 0.f, a2 = 0.f, a3 = 0.f;
#pragma unroll 8
    for (int l = 0; l < LL; ++l) {
        ushort4 v = *(const ushort4*)&vp[(size_t)l * RR];
        const float w = e_exp[l];
        a0 += w * bf2f(v.x); a1 += w * bf2f(v.y);
        a2 += w * bf2f(v.z); a3 += w * bf2f(v.w);
    }
    ushort* op = &afb[(size_t)b * RR + r4];
    op[0] = f2bf(a0 * inv); op[1] = f2bf(a1 * inv);
    op[2] = f2bf(a2 * inv); op[3] = f2bf(a3 * inv);
}

__global__ __launch_bounds__(256) void lstm_finish_kernel(
    const float* __restrict__ s, const float* __restrict__ c_in,
    const float* __restrict__ h_in, const float* __restrict__ mask,
    float* __restrict__ h_out, float* __restrict__ h_out2,
    float* __restrict__ c_out, ushort* __restrict__ h_bf)
{
    const int i = blockIdx.x * 256 + threadIdx.x;  // [0, B*R)
    const int b = i >> 10;
    const int r = i & 1023;
    const float* sb = &s[(size_t)b * 4 * RR];
    const float ig = fsigmoid(sb[r]);
    const float fg = fsigmoid(sb[RR + r]);
    const float og = fsigmoid(sb[2 * RR + r]);
    const float g  = ftanh(sb[3 * RR + r]);
    const float m = mask[b];
    const float c = c_in[i];
    float cn = fg * c + ig * g;
    cn = cn * m + c * (1.f - m);
    const float h = h_in[i];
    float hn = og * ftanh(cn);
    hn = hn * m + h * (1.f - m);
    h_out[i] = hn;
    if (h_out2) h_out2[i] = hn;
    c_out[i] = cn;
    if (h_bf) h_bf[i] = f2bf(hn);
}

extern "C" void kernel_launch(void* const* d_in, const int* in_sizes, int n_in,
                              void* d_out, int out_size, void* d_ws, size_t ws_size,
                              hipStream_t stream) {
    const float* xt   = (const float*)d_in[0];
    const float* mask = (const float*)d_in[1];
    const float* V    = (const float*)d_in[2];
    const float* pos  = (const float*)d_in[3];
    const float* h1   = (const float*)d_in[4];
    const float* c1   = (const float*)d_in[5];
    const float* h2   = (const float*)d_in[6];
    const float* c2   = (const float*)d_in[7];
    const float* Wg   = (const float*)d_in[8];
    const float* bg   = (const float*)d_in[9];
    const float* Wi1  = (const float*)d_in[10];
    const float* bi1  = (const float*)d_in[11];
    const float* Wa1  = (const float*)d_in[12];
    const float* ba1  = (const float*)d_in[13];
    const float* Wh1  = (const float*)d_in[14];
    const float* bh1  = (const float*)d_in[15];
    const float* Wi2  = (const float*)d_in[16];
    const float* bi2  = (const float*)d_in[17];
    const float* Wa2  = (const float*)d_in[18];
    const float* ba2  = (const float*)d_in[19];
    const float* Wh2  = (const float*)d_in[20];
    const float* bh2  = (const float*)d_in[21];
    const float* Wv2a = (const float*)d_in[22];
    const float* bv2a = (const float*)d_in[23];
    const float* Wh2a = (const float*)d_in[24];
    const float* bh2a = (const float*)d_in[25];
    const float* Wa2w = (const float*)d_in[26];
    const float* ba2w = (const float*)d_in[27];

    float* out = (float*)d_out;
    float* out2  = out;
    float* out1  = out + (size_t)BB * RR;
    float* c1n   = out + 2 * (size_t)BB * RR;
    float* out2b = out + 3 * (size_t)BB * RR;
    float* c2n   = out + 4 * (size_t)BB * RR;

    // ---- workspace layout: bf16 region then fp32 region ----
    ushort* wsu = (ushort*)d_ws;
    size_t o = 0;
    ushort* Vb     = wsu + o; o += (size_t)40960 * 1024;
    ushort* Wh2aT0 = wsu + o; o += (size_t)512 * 1024;
    ushort* Wh2aT1 = wsu + o; o += (size_t)512 * 1024;
    ushort* WgT    = wsu + o; o += (size_t)1024 * 1024;
    ushort* Wv2aT  = wsu + o; o += (size_t)512 * 1024;
    ushort* Wi1T   = wsu + o; o += (size_t)4096 * 1024;
    ushort* Wa1T   = wsu + o; o += (size_t)4096 * 1024;
    ushort* Wh1T   = wsu + o; o += (size_t)4096 * 1024;
    ushort* Wi2T   = wsu + o; o += (size_t)4096 * 1024;
    ushort* Wa2T   = wsu + o; o += (size_t)4096 * 1024;
    ushort* Wh2T   = wsu + o; o += (size_t)4096 * 1024;
    ushort* xtb    = wsu + o; o += (size_t)1024 * 1024;
    ushort* h1b    = wsu + o; o += (size_t)1024 * 1024;
    ushort* h2b    = wsu + o; o += (size_t)1024 * 1024;
    ushort* gpb    = wsu + o; o += (size_t)1024 * 1024;
    ushort* afb    = wsu + o; o += (size_t)1024 * 1024;
    ushort* out1b  = wsu + o; o += (size_t)1024 * 1024;
    float* wsf   = (float*)(wsu + o);
    float* hqf   = wsf;                    // 1024*512
    float* epart = hqf + 524288;           // 40960*4
    float* sbuf  = epart + 163840;         // 1024*4096 (aliased as split-K partials)
    float* partK = sbuf;

    const dim3 blk(256);

    // ---- conversion passes ----
    conv_bf16_kernel<<<dim3(20480), blk, 0, stream>>>(V, Vb, 5242880);
    {
        CP3 p; p.in[0] = xt; p.in[1] = h1; p.in[2] = h2;
        p.out[0] = xtb; p.out[1] = h1b; p.out[2] = h2b;
        conv_bf16_batch3_kernel<<<dim3(512, 3), blk, 0, stream>>>(p, 131072);
    }
    {
        TP6 p;
        p.in[0] = Wi1; p.in[1] = Wa1; p.in[2] = Wh1;
        p.in[3] = Wi2; p.in[4] = Wa2; p.in[5] = Wh2;
        p.out[0] = Wi1T; p.out[1] = Wa1T; p.out[2] = Wh1T;
        p.out[3] = Wi2T; p.out[4] = Wa2T; p.out[5] = Wh2T;
        for (int z = 0; z < 6; ++z) p.N[z] = 4096;
        transpose_conv_kernel<<<dim3(64, 16, 6), blk, 0, stream>>>(p);
    }
    {
        TP6 p;
        p.in[0] = Wh2a; p.in[1] = Wh2a + (size_t)1024 * 512;
        p.in[2] = Wg;   p.in[3] = Wv2a;
        p.out[0] = Wh2aT0; p.out[1] = Wh2aT1; p.out[2] = WgT; p.out[3] = Wv2aT;
        p.N[0] = 512; p.N[1] = 512; p.N[2] = 1024; p.N[3] = 512;
        p.in[4] = nullptr; p.in[5] = nullptr; p.out[4] = nullptr; p.out[5] = nullptr;
        p.N[4] = 0; p.N[5] = 0;
        transpose_conv_kernel<<<dim3(16, 16, 4), blk, 0, stream>>>(p);
    }

    // ---- hq = [h1,h2] @ Wh2a + bh2a (split-K x8 + reduce) ----
    gemm_bf16<2, 3, 8><<<dim3(4, 8, 8), blk, 0, stream>>>(
        h1b, h2b, nullptr, Wh2aT0, Wh2aT1, nullptr,
        nullptr, nullptr, nullptr, partK, 1024, 512, nullptr, nullptr, nullptr, nullptr);
    reduce_hq_kernel<<<dim3(2048), blk, 0, stream>>>(partK, bh2a, hqf);

    // ---- gate: xt @ Wg (split-K x4), fused relu*pos+pos -> bf16 ----
    gemm_bf16<1, 3, 4><<<dim3(8, 8, 4), blk, 0, stream>>>(
        xtb, nullptr, nullptr, WgT, nullptr, nullptr,
        nullptr, nullptr, nullptr, partK, 1024, 1024, nullptr, nullptr, nullptr, nullptr);
    reduce_gate_kernel<<<dim3(4096), blk, 0, stream>>>(partK, bg, pos, gpb);

    // ---- attention scores: V @ Wv2a, fused tanh-reduce -> epart ----
    gemm_bf16<1, 2, 1><<<dim3(4, 320, 1), blk, 0, stream>>>(
        Vb, nullptr, nullptr, Wv2aT, nullptr, nullptr,
        nullptr, nullptr, nullptr, nullptr, 40960, 512, hqf, bv2a, Wa2w, epart);
    softmax_af_kernel<<<dim3(BB), blk, 0, stream>>>(epart, Vb, ba2w, afb);

    // ---- LSTM layer 1 ----
    gemm_bf16<3, 0, 1><<<dim3(32, 8, 1), blk, 0, stream>>>(
        xtb, gpb, h1b, Wi1T, Wa1T, Wh1T, bi1, ba1, bh1,
        sbuf, 1024, 4096, nullptr, nullptr, nullptr, nullptr);
    lstm_finish_kernel<<<dim3(4096), blk, 0, stream>>>(sbuf, c1, h1, mask, out1, nullptr, c1n, out1b);

    // ---- LSTM layer 2 ----
    gemm_bf16<3, 0, 1><<<dim3(32, 8, 1), blk, 0, stream>>>(
        out1b, afb, h2b, Wi2T, Wa2T, Wh2T, bi2, ba2, bh2,
        sbuf, 1024, 4096, nullptr, nullptr, nullptr, nullptr);
    lstm_finish_kernel<<<dim3(4096), blk, 0, stream>>>(sbuf, c2, h2, mask, out2, out2b, c2n, nullptr);
}